// Round 22
// baseline (46.947 us; speedup 1.0000x reference)
//
#include <hip/hip_runtime.h>
#include <math.h>

// Shapes (hard-coded per reference setup_inputs):
//   b=16, t=128, c=t-1=127, kv_dim=k=64, h=4, q_dim=256
#define Bdim 16
#define Tdim 128
#define Cdim 127
#define Hdim 4
#define QD   256
#define HK   256   // h*k
#define BT   (Bdim * Tdim)

// ---- DPP ops (VALU pipe) ----
#define DPP_XOR1        0xB1   // quad_perm [1,0,3,2] : lane^1
#define DPP_XOR2        0x4E   // quad_perm [2,3,0,1] : lane^2
#define DPP_HALF_MIRROR 0x141  // mirror in 8  (== ^4 once bits0-1 uniform)
#define DPP_MIRROR      0x140  // mirror in 16 (== ^8 once bits0-2 uniform)
template<int CTRL>
__device__ __forceinline__ float dpp_movf(float x) {
    return __int_as_float(__builtin_amdgcn_update_dpp(
        0, __float_as_int(x), CTRL, 0xF, 0xF, true));
}
__device__ __forceinline__ float dot4(float4 a, float4 b, float s) {
    return fmaf(a.x, b.x, fmaf(a.y, b.y, fmaf(a.z, b.z, fmaf(a.w, b.w, s))));
}
__device__ __forceinline__ float4 fma4(float e, float4 x, float4 v) {
    v.x = fmaf(e, x.x, v.x); v.y = fmaf(e, x.y, v.y);
    v.z = fmaf(e, x.z, v.z); v.w = fmaf(e, x.w, v.w);
    return v;
}
__device__ __forceinline__ float4 add4(float4 a, float4 b) {
    return make_float4(a.x + b.x, a.y + b.y, a.z + b.z, a.w + b.w);
}
__device__ __forceinline__ float4 shfl4(float4 v, int m) {
    return make_float4(__shfl_xor(v.x, m, 64), __shfl_xor(v.y, m, 64),
                       __shfl_xor(v.z, m, 64), __shfl_xor(v.w, m, 64));
}
__device__ __forceinline__ float4 sel4(int c, float4 a, float4 b) {
    return c ? a : b;
}
// reduce a scalar over lane bits 0-3 (all-DPP, no LDS pipe)
__device__ __forceinline__ float red16(float v) {
    v += dpp_movf<DPP_XOR1>(v);
    v += dpp_movf<DPP_XOR2>(v);
    v += dpp_movf<DPP_HALF_MIRROR>(v);
    v += dpp_movf<DPP_MIRROR>(v);
    return v;
}

// ---------------------------------------------------------------------------
// K1: qk[bt, h*64+m] = sum_j (q_x[bt,:] @ Wq)[h*64+j] * Wk[m, h*64+j]
// (measured ~2.4 us including launch gap — unchanged)
__global__ __launch_bounds__(256) void qk_fused(
        const float* __restrict__ q_x,
        const float* __restrict__ Wq,
        const float* __restrict__ Wk,
        float* __restrict__ qk) {
    __shared__ __align__(16) float q_s[4][256];
    __shared__ __align__(16) float p_s[4][4][68];   // [row][head][j] padded
    int RB = blockIdx.x;
    int tid = threadIdx.x;
    {
        int r = tid >> 6, kq = tid & 63;
        *(float4*)&q_s[r][kq*4] =
            *(const float4*)(q_x + (size_t)(RB*4 + r) * QD + kq * 4);
    }
    __syncthreads();

    float acc[4] = {0.f, 0.f, 0.f, 0.f};
    #pragma unroll 4
    for (int i4 = 0; i4 < 64; ++i4) {
        float w0 = Wq[(size_t)(4*i4+0) * HK + tid];   // coalesced, L2-hot
        float w1 = Wq[(size_t)(4*i4+1) * HK + tid];
        float w2 = Wq[(size_t)(4*i4+2) * HK + tid];
        float w3 = Wq[(size_t)(4*i4+3) * HK + tid];
        #pragma unroll
        for (int r = 0; r < 4; ++r) {
            float4 qv = *(const float4*)&q_s[r][i4*4];   // b128 broadcast
            acc[r] = fmaf(qv.x, w0, fmaf(qv.y, w1, fmaf(qv.z, w2, fmaf(qv.w, w3, acc[r]))));
        }
    }
    int h = tid >> 6, m = tid & 63;
    #pragma unroll
    for (int r = 0; r < 4; ++r) p_s[r][h][m] = acc[r];
    __syncthreads();

    const float4* wk4 = (const float4*)(Wk + (size_t)m * HK + h * 64);
    float4 wkr[16];
    #pragma unroll
    for (int j = 0; j < 16; ++j) wkr[j] = wk4[j];       // L2-hot, 64 KB total
    float a2[4] = {0.f, 0.f, 0.f, 0.f};
    #pragma unroll
    for (int j4 = 0; j4 < 16; ++j4) {
        #pragma unroll
        for (int r = 0; r < 4; ++r) {
            float4 pv = *(const float4*)&p_s[r][h][j4*4];  // wave-uniform bcast
            a2[r] = fmaf(pv.x, wkr[j4].x, fmaf(pv.y, wkr[j4].y,
                    fmaf(pv.z, wkr[j4].z, fmaf(pv.w, wkr[j4].w, a2[r]))));
        }
    }
    #pragma unroll
    for (int r = 0; r < 4; ++r)
        qk[(size_t)(RB*4 + r) * HK + tid] = a2[r];      // coalesced
}

// ---------------------------------------------------------------------------
// K2: attn_fused — single pass over X with COPY-STYLE loads: lane =
// (rr = lane>>4 row-of-4, ff = lane&15 chunk), so every load instruction
// covers EXACTLY ONE contiguous, fully-consumed 1 KB block (like the
// 6.3 TB/s copy ubench; r19-r21's layouts touched 64 sectors/KB using
// 16B of each — 4x the sector-lookup cost if that's the per-CU limiter).
// 4 waves per bt (wave wv owns rows 32wv..32wv+31), 2048 blocks,
// ~70 VGPR -> 24 waves/CU. Zero barriers in the stream; single post-load
// barrier for the 4-wave LDS combine + fused V-projection epilogue.
__global__ __launch_bounds__(256, 6) void attn_fused(
        const float* __restrict__ kv_x,
        const float* __restrict__ qk_g,
        const float* __restrict__ Wv,
        float* __restrict__ out) {
    __shared__ __align__(16) float4 wx_p[4][4][16];   // [wave][head][chunk] 4KB
    __shared__ __align__(16) float4 dn_p[4];          // [wave] heads 0..3

    int tid = threadIdx.x;
    int wv = tid >> 6, lane = tid & 63;
    int bt = blockIdx.x;
    int rr = lane >> 4;           // row within the 1KB block (0..3)
    int ff = lane & 15;           // float4 chunk within the row
    int cbase = wv * 32;          // this wave's first row
    const float* Xr = kv_x + (size_t)bt * (Cdim * 64);

    // all 4 heads' qk chunk ff -> 4 float4 regs (dup over rr: merged)
    const float4* qb = (const float4*)(qk_g + (size_t)bt * HK);
    float4 Q0 = qb[0*16 + ff], Q1 = qb[1*16 + ff],
           Q2 = qb[2*16 + ff], Q3 = qb[3*16 + ff];

    float4 V0 = {0,0,0,0}, V1 = {0,0,0,0}, V2 = {0,0,0,0}, V3 = {0,0,0,0};
    float d0 = 0.f, d1 = 0.f, d2 = 0.f, d3 = 0.f;
    float4 A, B, C, D;

#define LOADP(P,KK) do {                                                     \
    int c_ = cbase + 4*(KK) + rr;                                            \
    P = *((const float4*)(Xr + (size_t)((c_ < Cdim) ? c_ : 0) * 64) + ff);   \
} while (0)

#define COMP(P,KK) do {                                                      \
    float s0 = dot4(Q0, P, 0.f);                                             \
    float s1 = dot4(Q1, P, 0.f);                                             \
    float s2 = dot4(Q2, P, 0.f);                                             \
    float s3 = dot4(Q3, P, 0.f);                                             \
    s0 = red16(s0); s1 = red16(s1); s2 = red16(s2); s3 = red16(s3);          \
    bool vld_ = (cbase + 4*(KK) + rr) < Cdim;                                \
    float e0 = vld_ ? __expf(s0 * 0.125f) : 0.f;                             \
    float e1 = vld_ ? __expf(s1 * 0.125f) : 0.f;                             \
    float e2 = vld_ ? __expf(s2 * 0.125f) : 0.f;                             \
    float e3 = vld_ ? __expf(s3 * 0.125f) : 0.f;                             \
    d0 += e0; d1 += e1; d2 += e2; d3 += e3;                                  \
    V0 = fma4(e0, P, V0); V1 = fma4(e1, P, V1);                              \
    V2 = fma4(e2, P, V2); V3 = fma4(e3, P, V3);                              \
} while (0)

    // 4-deep hand pipeline: one contiguous 1KB block per load instruction
    LOADP(A,0);
    LOADP(B,1);
    LOADP(C,2);
    LOADP(D,3);
    COMP (A,0);
    LOADP(A,4);
    COMP (B,1);
    LOADP(B,5);
    COMP (C,2);
    LOADP(C,6);
    COMP (D,3);
    LOADP(D,7);
    COMP (A,4);
    COMP (B,5);
    COMP (C,6);
    COMP (D,7);
#undef LOADP
#undef COMP

    // ---- splitting butterfly over rr (lane bits 4-5): ends with one head
    // per lane; lane (r5,r4,ff) owns head H=(r5<<1)|r4, chunk ff ----
    int r4 = (lane >> 4) & 1, r5 = (lane >> 5) & 1;
    float4 G0 = add4(sel4(r4, V1, V0), shfl4(sel4(r4, V0, V1), 16));
    float4 G1 = add4(sel4(r4, V3, V2), shfl4(sel4(r4, V2, V3), 16));
    float4 F  = add4(sel4(r5, G1, G0), shfl4(sel4(r5, G0, G1), 32));
    int H = (r5 << 1) | r4;
    wx_p[wv][H][ff] = F;                          // 64 lanes -> 64 chunks

    // denom: reduce over rr bits (ff lanes hold duplicates - never reduced)
    d0 += __shfl_xor(d0, 16, 64); d0 += __shfl_xor(d0, 32, 64);
    d1 += __shfl_xor(d1, 16, 64); d1 += __shfl_xor(d1, 32, 64);
    d2 += __shfl_xor(d2, 16, 64); d2 += __shfl_xor(d2, 32, 64);
    d3 += __shfl_xor(d3, 16, 64); d3 += __shfl_xor(d3, 32, 64);
    if (lane == 0) dn_p[wv] = make_float4(d0, d1, d2, d3);
    __syncthreads();    // single barrier: AFTER all global loads consumed

    // ---- fused V-projection epilogue: thread = output column ----
    {
        int h = tid >> 6, col = tid;              // h == wave index
        float4 n0 = dn_p[0], n1 = dn_p[1], n2 = dn_p[2], n3 = dn_p[3];
        float4 ns = make_float4(n0.x+n1.x+n2.x+n3.x, n0.y+n1.y+n2.y+n3.y,
                                n0.z+n1.z+n2.z+n3.z, n0.w+n1.w+n2.w+n3.w);
        float dn = (h == 0) ? ns.x : (h == 1) ? ns.y
                 : (h == 2) ? ns.z : ns.w;        // wave-uniform select
        float inv = 1.f / dn;
        const float* wvc = Wv + col;              // coalesced, L2-hot (64 KB)
        float acc = 0.f;
        #pragma unroll
        for (int f4 = 0; f4 < 16; ++f4) {
            float4 w = add4(add4(wx_p[0][h][f4], wx_p[1][h][f4]),
                            add4(wx_p[2][h][f4], wx_p[3][h][f4]));
            int j = f4 * 4;
            acc = fmaf(w.x, wvc[(size_t)(j+0) * HK],
                  fmaf(w.y, wvc[(size_t)(j+1) * HK],
                  fmaf(w.z, wvc[(size_t)(j+2) * HK],
                  fmaf(w.w, wvc[(size_t)(j+3) * HK], acc))));
        }
        out[(size_t)bt * HK + col] = acc * inv;   // coalesced
    }
}

extern "C" void kernel_launch(void* const* d_in, const int* in_sizes, int n_in,
                              void* d_out, int out_size, void* d_ws, size_t ws_size,
                              hipStream_t stream) {
    const float* q_x  = (const float*)d_in[0];   // [16,128,256]
    const float* kv_x = (const float*)d_in[1];   // [16,128,127,64]
    const float* Wq   = (const float*)d_in[2];   // [256,256]
    const float* Wk   = (const float*)d_in[3];   // [64,256]
    const float* Wv   = (const float*)d_in[4];   // [64,256]
    float* out = (float*)d_out;                  // [16,128,256] f32

    float* qk = (float*)d_ws;                    // BT*HK floats = 2 MB

    qk_fused <<<BT / 4, 256, 0, stream>>>(q_x, Wq, Wk, qk);
    attn_fused<<<BT, 256, 0, stream>>>(kv_x, qk, Wv, out);
}

// Round 23
// 36.873 us; speedup vs baseline: 1.2732x; 1.2732x over previous
//
#include <hip/hip_runtime.h>
#include <math.h>

// Shapes (hard-coded per reference setup_inputs):
//   b=16, t=128, c=t-1=127, kv_dim=k=64, h=4, q_dim=256
#define Bdim 16
#define Tdim 128
#define Cdim 127
#define Hdim 4
#define QD   256
#define HK   256   // h*k
#define BT   (Bdim * Tdim)

// ---- DPP quad ops (VALU pipe) ----
#define DPP_XOR1 0xB1   // quad_perm [1,0,3,2] : lane^1
#define DPP_XOR2 0x4E   // quad_perm [2,3,0,1] : lane^2
template<int CTRL>
__device__ __forceinline__ float dpp_movf(float x) {
    return __int_as_float(__builtin_amdgcn_update_dpp(
        0, __float_as_int(x), CTRL, 0xF, 0xF, true));
}
__device__ __forceinline__ float dot4(float4 a, float4 b, float s) {
    return fmaf(a.x, b.x, fmaf(a.y, b.y, fmaf(a.z, b.z, fmaf(a.w, b.w, s))));
}
__device__ __forceinline__ float4 fma4(float e, float4 x, float4 v) {
    v.x = fmaf(e, x.x, v.x); v.y = fmaf(e, x.y, v.y);
    v.z = fmaf(e, x.z, v.z); v.w = fmaf(e, x.w, v.w);
    return v;
}
__device__ __forceinline__ float4 add4(float4 a, float4 b) {
    return make_float4(a.x + b.x, a.y + b.y, a.z + b.z, a.w + b.w);
}
__device__ __forceinline__ float4 shfl4(float4 v, int m) {
    return make_float4(__shfl_xor(v.x, m, 64), __shfl_xor(v.y, m, 64),
                       __shfl_xor(v.z, m, 64), __shfl_xor(v.w, m, 64));
}
__device__ __forceinline__ float4 sel4(int c, float4 a, float4 b) {
    return c ? a : b;
}

// ---------------------------------------------------------------------------
// K1: qk[bt, h*64+m] = sum_j (q_x[bt,:] @ Wq)[h*64+j] * Wk[m, h*64+j]
// (measured ~2.4 us including launch gap — unchanged)
__global__ __launch_bounds__(256) void qk_fused(
        const float* __restrict__ q_x,
        const float* __restrict__ Wq,
        const float* __restrict__ Wk,
        float* __restrict__ qk) {
    __shared__ __align__(16) float q_s[4][256];
    __shared__ __align__(16) float p_s[4][4][68];   // [row][head][j] padded
    int RB = blockIdx.x;
    int tid = threadIdx.x;
    {
        int r = tid >> 6, kq = tid & 63;
        *(float4*)&q_s[r][kq*4] =
            *(const float4*)(q_x + (size_t)(RB*4 + r) * QD + kq * 4);
    }
    __syncthreads();

    float acc[4] = {0.f, 0.f, 0.f, 0.f};
    #pragma unroll 4
    for (int i4 = 0; i4 < 64; ++i4) {
        float w0 = Wq[(size_t)(4*i4+0) * HK + tid];   // coalesced, L2-hot
        float w1 = Wq[(size_t)(4*i4+1) * HK + tid];
        float w2 = Wq[(size_t)(4*i4+2) * HK + tid];
        float w3 = Wq[(size_t)(4*i4+3) * HK + tid];
        #pragma unroll
        for (int r = 0; r < 4; ++r) {
            float4 qv = *(const float4*)&q_s[r][i4*4];   // b128 broadcast
            acc[r] = fmaf(qv.x, w0, fmaf(qv.y, w1, fmaf(qv.z, w2, fmaf(qv.w, w3, acc[r]))));
        }
    }
    int h = tid >> 6, m = tid & 63;
    #pragma unroll
    for (int r = 0; r < 4; ++r) p_s[r][h][m] = acc[r];
    __syncthreads();

    const float4* wk4 = (const float4*)(Wk + (size_t)m * HK + h * 64);
    float4 wkr[16];
    #pragma unroll
    for (int j = 0; j < 16; ++j) wkr[j] = wk4[j];       // L2-hot, 64 KB total
    float a2[4] = {0.f, 0.f, 0.f, 0.f};
    #pragma unroll
    for (int j4 = 0; j4 < 16; ++j4) {
        #pragma unroll
        for (int r = 0; r < 4; ++r) {
            float4 pv = *(const float4*)&p_s[r][h][j4*4];  // wave-uniform bcast
            a2[r] = fmaf(pv.x, wkr[j4].x, fmaf(pv.y, wkr[j4].y,
                    fmaf(pv.z, wkr[j4].z, fmaf(pv.w, wkr[j4].w, a2[r]))));
        }
    }
    #pragma unroll
    for (int r = 0; r < 4; ++r)
        qk[(size_t)(RB*4 + r) * HK + tid] = a2[r];      // coalesced
}

// ---------------------------------------------------------------------------
// K2: attn_fused — r21 skeleton (2 heads/wave, 2 bt/block, 16 waves/CU,
// single-pass no-max softmax) with DUAL-PATH loads: rows 64-127 stream via
// the global_load_lds DMA engine (issued at t=0, fire-and-forget,
// pre-swizzled global source p^(c&7) + linear LDS dest), rows 0-63 via the
// proven VGPR-return pipeline. If the two paths have separate per-CU
// request capacity, aggregate read BW ~doubles; if shared, this is ~flat
// vs r21 (the decisive test for the ~2.2 TB/s read wall).
__global__ __launch_bounds__(256, 4) void attn_fused(
        const float* __restrict__ kv_x,
        const float* __restrict__ qk_g,
        const float* __restrict__ Wv,
        float* __restrict__ out) {
    __shared__ __align__(16) float4 sX[2][64 * 16];  // rows 64..127/slot: 32KB
    __shared__ __align__(16) float4 wx_s[2][4][16];  // [slot][head][chunk] 2KB
    __shared__ float dn_s[2][4];

    int tid = threadIdx.x;
    int wv = tid >> 6, lane = tid & 63;
    int slot = wv >> 1;           // which bt of this block
    int hp   = wv & 1;            // head-pair: heads 2hp, 2hp+1
    int bt = blockIdx.x * 2 + slot;
    int r  = lane >> 2;           // row-slot 0..15
    int jq = lane & 3;            // quarter of the row
    const float* Xr = kv_x + (size_t)bt * (Cdim * 64);
    const float4* Xr4 = (const float4*)Xr;

    // ---- DMA path: stage rows 64+hp*32 .. 64+hp*32+31 into LDS ----
    // chunk l = hp*512 + t*64 + lane; LDS linear, global source swizzled so
    // LDS[(c-64)*16 + p] = X[c][p ^ (c&7)] (m173 pattern). Row 127 staged
    // from row 126 (finite garbage; e[127]=0 masks it).
    #pragma unroll
    for (int t = 0; t < 8; ++t) {
        int l = hp * 512 + t * 64 + lane;
        int c = 64 + (l >> 4), p = l & 15;
        int csrc = (c < Cdim) ? c : (Cdim - 1);
        __builtin_amdgcn_global_load_lds(
            (const __attribute__((address_space(1))) void*)
                (Xr4 + (size_t)csrc * 16 + (p ^ (c & 7))),
            (__attribute__((address_space(3))) void*)(&sX[slot][l]), 16, 0, 0);
    }

    // this wave's 2 heads, quarter jq -> 8 float4 regs
    const float4* qb = (const float4*)(qk_g + (size_t)bt * HK);
    float4 Q00 = qb[(2*hp+0)*16 + jq*4 + 0], Q01 = qb[(2*hp+0)*16 + jq*4 + 1],
           Q02 = qb[(2*hp+0)*16 + jq*4 + 2], Q03 = qb[(2*hp+0)*16 + jq*4 + 3];
    float4 Q10 = qb[(2*hp+1)*16 + jq*4 + 0], Q11 = qb[(2*hp+1)*16 + jq*4 + 1],
           Q12 = qb[(2*hp+1)*16 + jq*4 + 2], Q13 = qb[(2*hp+1)*16 + jq*4 + 3];

    float4 V00={0,0,0,0},V01={0,0,0,0},V02={0,0,0,0},V03={0,0,0,0};
    float4 V10={0,0,0,0},V11={0,0,0,0},V12={0,0,0,0},V13={0,0,0,0};
    float d0=0.f, d1=0.f;
    float4 A0, A1, A2, A3, B0, B1, B2, B3;

#define LOADR(P0,P1,P2,P3,KK) do {                                           \
    int c_ = 16*(KK) + r;                       /* KK<=3: always < 64 */     \
    const float4* xp_ = Xr4 + (size_t)c_ * 16 + jq * 4;                      \
    P0 = xp_[0]; P1 = xp_[1]; P2 = xp_[2]; P3 = xp_[3];                      \
} while (0)

#define LOADL(P0,P1,P2,P3,KK) do {                                           \
    int c_ = 16*(KK) + r;                       /* 64..127 */                \
    const float4* lb_ = &sX[slot][(c_ - 64) * 16];                           \
    int sw_ = c_ & 7;                           /* == r&7 */                 \
    P0 = lb_[(jq*4 + 0) ^ sw_];                                              \
    P1 = lb_[(jq*4 + 1) ^ sw_];                                              \
    P2 = lb_[(jq*4 + 2) ^ sw_];                                              \
    P3 = lb_[(jq*4 + 3) ^ sw_];                                              \
} while (0)

#define COMP(P0,P1,P2,P3,KK) do {                                            \
    float s0 = dot4(Q00,P0,0.f); s0 = dot4(Q01,P1,s0);                       \
    s0 = dot4(Q02,P2,s0); s0 = dot4(Q03,P3,s0);                              \
    float s1 = dot4(Q10,P0,0.f); s1 = dot4(Q11,P1,s1);                       \
    s1 = dot4(Q12,P2,s1); s1 = dot4(Q13,P3,s1);                              \
    s0 += dpp_movf<DPP_XOR1>(s0); s0 += dpp_movf<DPP_XOR2>(s0);              \
    s1 += dpp_movf<DPP_XOR1>(s1); s1 += dpp_movf<DPP_XOR2>(s1);              \
    bool vld_ = (16*(KK) + r) < Cdim;                                        \
    float e0 = vld_ ? __expf(s0 * 0.125f) : 0.f;                             \
    float e1 = vld_ ? __expf(s1 * 0.125f) : 0.f;                             \
    d0 += e0; d1 += e1;                                                      \
    V00=fma4(e0,P0,V00); V01=fma4(e0,P1,V01);                                \
    V02=fma4(e0,P2,V02); V03=fma4(e0,P3,V03);                                \
    V10=fma4(e1,P0,V10); V11=fma4(e1,P1,V11);                                \
    V12=fma4(e1,P2,V12); V13=fma4(e1,P3,V13);                                \
} while (0)

    // ---- phase 1: rows 0..63 via VGPR path (2-deep pipeline) ----
    LOADR(A0,A1,A2,A3,0);
    LOADR(B0,B1,B2,B3,1);
    COMP (A0,A1,A2,A3,0);
    LOADR(A0,A1,A2,A3,2);
    COMP (B0,B1,B2,B3,1);
    LOADR(B0,B1,B2,B3,3);
    COMP (A0,A1,A2,A3,2);
    COMP (B0,B1,B2,B3,3);

    __syncthreads();   // barrier #1: drains DMA -> sX valid

    // ---- phase 2: rows 64..127 from LDS (DMA-staged) ----
    LOADL(A0,A1,A2,A3,4);
    LOADL(B0,B1,B2,B3,5);
    COMP (A0,A1,A2,A3,4);
    LOADL(A0,A1,A2,A3,6);
    COMP (B0,B1,B2,B3,5);
    LOADL(B0,B1,B2,B3,7);
    COMP (A0,A1,A2,A3,6);
    COMP (B0,B1,B2,B3,7);
#undef LOADR
#undef LOADL
#undef COMP

    // ---- splitting butterfly over r bits (lane bits 2-5) ----
    int r0 = (lane >> 2) & 1, r1 = (lane >> 3) & 1;
    int r2 = (lane >> 4) & 1, r3 = (lane >> 5) & 1;
    float4 K00 = add4(sel4(r0, V01, V00), shfl4(sel4(r0, V00, V01), 4));
    float4 K01 = add4(sel4(r0, V03, V02), shfl4(sel4(r0, V02, V03), 4));
    float4 K10 = add4(sel4(r0, V11, V10), shfl4(sel4(r0, V10, V11), 4));
    float4 K11 = add4(sel4(r0, V13, V12), shfl4(sel4(r0, V12, V13), 4));
    float4 L0 = add4(sel4(r1, K01, K00), shfl4(sel4(r1, K00, K01), 8));
    float4 L1 = add4(sel4(r1, K11, K10), shfl4(sel4(r1, K10, K11), 8));
    float4 M = add4(sel4(r2, L1, L0), shfl4(sel4(r2, L0, L1), 16));
    float4 F = add4(M, shfl4(M, 32));

    // denom butterfly over r bits
    #pragma unroll
    for (int m = 4; m <= 32; m <<= 1) {
        d0 += __shfl_xor(d0, m, 64);
        d1 += __shfl_xor(d1, m, 64);
    }

    int H  = 2*hp + r2;
    int qo = (r1 << 1) | r0;
    if (r3 == 0) wx_s[slot][H][jq * 4 + qo] = F;   // 32 lanes, 32 chunks
    if (lane == 0) { dn_s[slot][2*hp+0] = d0; dn_s[slot][2*hp+1] = d1; }
    __syncthreads();   // barrier #2: wx/dn visible

    // ---- fused V-projection epilogue: 2 passes (one per slot) ----
    #pragma unroll
    for (int s = 0; s < 2; ++s) {
        int col = tid;                   // 0..255 = h*64 + k
        int h = col >> 6;                // wave-uniform
        float inv = 1.f / dn_s[s][h];
        const float* wvc = Wv + col;     // Wv[j*HK + col], coalesced, L2-hot
        float acc = 0.f;
        #pragma unroll
        for (int j4 = 0; j4 < 16; ++j4) {
            float4 w4 = wx_s[s][h][j4];  // wave-uniform broadcast
            acc = fmaf(w4.x, wvc[(size_t)(j4*4+0) * HK],
                  fmaf(w4.y, wvc[(size_t)(j4*4+1) * HK],
                  fmaf(w4.z, wvc[(size_t)(j4*4+2) * HK],
                  fmaf(w4.w, wvc[(size_t)(j4*4+3) * HK], acc))));
        }
        out[(size_t)(blockIdx.x * 2 + s) * HK + col] = acc * inv;
    }
}

extern "C" void kernel_launch(void* const* d_in, const int* in_sizes, int n_in,
                              void* d_out, int out_size, void* d_ws, size_t ws_size,
                              hipStream_t stream) {
    const float* q_x  = (const float*)d_in[0];   // [16,128,256]
    const float* kv_x = (const float*)d_in[1];   // [16,128,127,64]
    const float* Wq   = (const float*)d_in[2];   // [256,256]
    const float* Wk   = (const float*)d_in[3];   // [64,256]
    const float* Wv   = (const float*)d_in[4];   // [64,256]
    float* out = (float*)d_out;                  // [16,128,256] f32

    float* qk = (float*)d_ws;                    // BT*HK floats = 2 MB

    qk_fused <<<BT / 4, 256, 0, stream>>>(q_x, Wq, Wk, qk);
    attn_fused<<<BT / 2, 256, 0, stream>>>(kv_x, qk, Wv, out);
}

// Round 24
// 36.438 us; speedup vs baseline: 1.2884x; 1.0119x over previous
//
#include <hip/hip_runtime.h>
#include <math.h>

// Shapes (hard-coded per reference setup_inputs):
//   b=16, t=128, c=t-1=127, kv_dim=k=64, h=4, q_dim=256
#define Bdim 16
#define Tdim 128
#define Cdim 127
#define Hdim 4
#define QD   256
#define HK   256   // h*k
#define BT   (Bdim * Tdim)

// ---- DPP quad ops (VALU pipe) ----
#define DPP_XOR1 0xB1   // quad_perm [1,0,3,2] : lane^1
#define DPP_XOR2 0x4E   // quad_perm [2,3,0,1] : lane^2
template<int CTRL>
__device__ __forceinline__ float dpp_movf(float x) {
    return __int_as_float(__builtin_amdgcn_update_dpp(
        0, __float_as_int(x), CTRL, 0xF, 0xF, true));
}
__device__ __forceinline__ float dot4(float4 a, float4 b, float s) {
    return fmaf(a.x, b.x, fmaf(a.y, b.y, fmaf(a.z, b.z, fmaf(a.w, b.w, s))));
}
__device__ __forceinline__ float4 fma4(float e, float4 x, float4 v) {
    v.x = fmaf(e, x.x, v.x); v.y = fmaf(e, x.y, v.y);
    v.z = fmaf(e, x.z, v.z); v.w = fmaf(e, x.w, v.w);
    return v;
}
__device__ __forceinline__ float4 add4(float4 a, float4 b) {
    return make_float4(a.x + b.x, a.y + b.y, a.z + b.z, a.w + b.w);
}
__device__ __forceinline__ float4 shfl4(float4 v, int m) {
    return make_float4(__shfl_xor(v.x, m, 64), __shfl_xor(v.y, m, 64),
                       __shfl_xor(v.z, m, 64), __shfl_xor(v.w, m, 64));
}
__device__ __forceinline__ float4 sel4(int c, float4 a, float4 b) {
    return c ? a : b;
}

// ---------------------------------------------------------------------------
// K1: qk[bt, h*64+m] = sum_j (q_x[bt,:] @ Wq)[h*64+j] * Wk[m, h*64+j]
// (measured ~2.4 us including launch gap)
__global__ __launch_bounds__(256) void qk_fused(
        const float* __restrict__ q_x,
        const float* __restrict__ Wq,
        const float* __restrict__ Wk,
        float* __restrict__ qk) {
    __shared__ __align__(16) float q_s[4][256];
    __shared__ __align__(16) float p_s[4][4][68];   // [row][head][j] padded
    int RB = blockIdx.x;
    int tid = threadIdx.x;
    {
        int r = tid >> 6, kq = tid & 63;
        *(float4*)&q_s[r][kq*4] =
            *(const float4*)(q_x + (size_t)(RB*4 + r) * QD + kq * 4);
    }
    __syncthreads();

    float acc[4] = {0.f, 0.f, 0.f, 0.f};
    #pragma unroll 4
    for (int i4 = 0; i4 < 64; ++i4) {
        float w0 = Wq[(size_t)(4*i4+0) * HK + tid];   // coalesced, L2-hot
        float w1 = Wq[(size_t)(4*i4+1) * HK + tid];
        float w2 = Wq[(size_t)(4*i4+2) * HK + tid];
        float w3 = Wq[(size_t)(4*i4+3) * HK + tid];
        #pragma unroll
        for (int r = 0; r < 4; ++r) {
            float4 qv = *(const float4*)&q_s[r][i4*4];   // b128 broadcast
            acc[r] = fmaf(qv.x, w0, fmaf(qv.y, w1, fmaf(qv.z, w2, fmaf(qv.w, w3, acc[r]))));
        }
    }
    int h = tid >> 6, m = tid & 63;
    #pragma unroll
    for (int r = 0; r < 4; ++r) p_s[r][h][m] = acc[r];
    __syncthreads();

    const float4* wk4 = (const float4*)(Wk + (size_t)m * HK + h * 64);
    float4 wkr[16];
    #pragma unroll
    for (int j = 0; j < 16; ++j) wkr[j] = wk4[j];       // L2-hot, 64 KB total
    float a2[4] = {0.f, 0.f, 0.f, 0.f};
    #pragma unroll
    for (int j4 = 0; j4 < 16; ++j4) {
        #pragma unroll
        for (int r = 0; r < 4; ++r) {
            float4 pv = *(const float4*)&p_s[r][h][j4*4];  // wave-uniform bcast
            a2[r] = fmaf(pv.x, wkr[j4].x, fmaf(pv.y, wkr[j4].y,
                    fmaf(pv.z, wkr[j4].z, fmaf(pv.w, wkr[j4].w, a2[r]))));
        }
    }
    #pragma unroll
    for (int r = 0; r < 4; ++r)
        qk[(size_t)(RB*4 + r) * HK + tid] = a2[r];      // coalesced
}

// ---------------------------------------------------------------------------
// K2: attn_fused — single-pass no-max-softmax core (score->exp->accumulate
// while the row is in registers; X read from HBM exactly once), 2 heads per
// wave (Q 8 f4, V 8 f4, ~116 VGPR -> 16 waves/CU), 2 bt per block, 64
// distinct 64B lines per load instruction, 2-deep hand pipeline, zero
// barriers in the stream; single post-load barrier + fused V-projection.
// Measured r21: 35.56 us total (best). The ~2.2-2.5 TB/s delivered-read
// wall was probed on every axis (occupancy r18, barriers r14, traffic r16,
// line coverage r19, sectors r22, dual-path r23) — structural for this op.
__global__ __launch_bounds__(256, 4) void attn_fused(
        const float* __restrict__ kv_x,
        const float* __restrict__ qk_g,
        const float* __restrict__ Wv,
        float* __restrict__ out) {
    __shared__ __align__(16) float4 wx_s[2][4][16];  // [slot][head][chunk] 2KB
    __shared__ float dn_s[2][4];
    int tid = threadIdx.x;
    int wv = tid >> 6, lane = tid & 63;
    int slot = wv >> 1;           // which bt of this block
    int hp   = wv & 1;            // head-pair: heads 2hp, 2hp+1
    int bt = blockIdx.x * 2 + slot;
    int r  = lane >> 2;           // row-slot 0..15
    int jq = lane & 3;            // quarter of the row
    const float* Xr = kv_x + (size_t)bt * (Cdim * 64);

    // this wave's 2 heads, quarter jq -> 8 float4 regs
    const float4* qb = (const float4*)(qk_g + (size_t)bt * HK);
    float4 Q00 = qb[(2*hp+0)*16 + jq*4 + 0], Q01 = qb[(2*hp+0)*16 + jq*4 + 1],
           Q02 = qb[(2*hp+0)*16 + jq*4 + 2], Q03 = qb[(2*hp+0)*16 + jq*4 + 3];
    float4 Q10 = qb[(2*hp+1)*16 + jq*4 + 0], Q11 = qb[(2*hp+1)*16 + jq*4 + 1],
           Q12 = qb[(2*hp+1)*16 + jq*4 + 2], Q13 = qb[(2*hp+1)*16 + jq*4 + 3];

    float4 V00={0,0,0,0},V01={0,0,0,0},V02={0,0,0,0},V03={0,0,0,0};
    float4 V10={0,0,0,0},V11={0,0,0,0},V12={0,0,0,0},V13={0,0,0,0};
    float d0=0.f, d1=0.f;
    float4 A0, A1, A2, A3, B0, B1, B2, B3;

#define LOADR(P0,P1,P2,P3,KK) do {                                           \
    int c_ = 16*(KK) + r;                                                    \
    const float4* xp_ = (const float4*)(Xr + (size_t)((c_ < Cdim) ? c_ : 0)  \
                                        * 64) + jq * 4;                      \
    P0 = xp_[0]; P1 = xp_[1]; P2 = xp_[2]; P3 = xp_[3];                      \
} while (0)

#define COMP(P0,P1,P2,P3,KK) do {                                            \
    float s0 = dot4(Q00,P0,0.f); s0 = dot4(Q01,P1,s0);                       \
    s0 = dot4(Q02,P2,s0); s0 = dot4(Q03,P3,s0);                              \
    float s1 = dot4(Q10,P0,0.f); s1 = dot4(Q11,P1,s1);                       \
    s1 = dot4(Q12,P2,s1); s1 = dot4(Q13,P3,s1);                              \
    s0 += dpp_movf<DPP_XOR1>(s0); s0 += dpp_movf<DPP_XOR2>(s0);              \
    s1 += dpp_movf<DPP_XOR1>(s1); s1 += dpp_movf<DPP_XOR2>(s1);              \
    bool vld_ = (16*(KK) + r) < Cdim;                                        \
    float e0 = vld_ ? __expf(s0 * 0.125f) : 0.f;                             \
    float e1 = vld_ ? __expf(s1 * 0.125f) : 0.f;                             \
    d0 += e0; d1 += e1;                                                      \
    V00=fma4(e0,P0,V00); V01=fma4(e0,P1,V01);                                \
    V02=fma4(e0,P2,V02); V03=fma4(e0,P3,V03);                                \
    V10=fma4(e1,P0,V10); V11=fma4(e1,P1,V11);                                \
    V12=fma4(e1,P2,V12); V13=fma4(e1,P3,V13);                                \
} while (0)

    // 2-deep hand pipeline (8 b128 in flight per lane)
    LOADR(A0,A1,A2,A3,0);
    LOADR(B0,B1,B2,B3,1);
    COMP (A0,A1,A2,A3,0);
    LOADR(A0,A1,A2,A3,2);
    COMP (B0,B1,B2,B3,1);
    LOADR(B0,B1,B2,B3,3);
    COMP (A0,A1,A2,A3,2);
    LOADR(A0,A1,A2,A3,4);
    COMP (B0,B1,B2,B3,3);
    LOADR(B0,B1,B2,B3,5);
    COMP (A0,A1,A2,A3,4);
    LOADR(A0,A1,A2,A3,6);
    COMP (B0,B1,B2,B3,5);
    LOADR(B0,B1,B2,B3,7);
    COMP (A0,A1,A2,A3,6);
    COMP (B0,B1,B2,B3,7);
#undef LOADR
#undef COMP

    // ---- splitting butterfly over r bits (lane bits 2-5) ----
    int r0 = (lane >> 2) & 1, r1 = (lane >> 3) & 1;
    int r2 = (lane >> 4) & 1, r3 = (lane >> 5) & 1;
    // Round 1 (xor 4): keep q with (q&1)==r0
    float4 K00 = add4(sel4(r0, V01, V00), shfl4(sel4(r0, V00, V01), 4));
    float4 K01 = add4(sel4(r0, V03, V02), shfl4(sel4(r0, V02, V03), 4));
    float4 K10 = add4(sel4(r0, V11, V10), shfl4(sel4(r0, V10, V11), 4));
    float4 K11 = add4(sel4(r0, V13, V12), shfl4(sel4(r0, V12, V13), 4));
    // Round 2 (xor 8): keep p==r1 -> per head one chunk, qo=(r1<<1)|r0
    float4 L0 = add4(sel4(r1, K01, K00), shfl4(sel4(r1, K00, K01), 8));
    float4 L1 = add4(sel4(r1, K11, K10), shfl4(sel4(r1, K10, K11), 8));
    // Round 3 (xor 16): split the 2 heads by r2
    float4 M = add4(sel4(r2, L1, L0), shfl4(sel4(r2, L0, L1), 16));
    // Round 4 (xor 32): plain sum (r3 copies identical)
    float4 F = add4(M, shfl4(M, 32));

    // denom butterfly over r bits
    #pragma unroll
    for (int m = 4; m <= 32; m <<= 1) {
        d0 += __shfl_xor(d0, m, 64);
        d1 += __shfl_xor(d1, m, 64);
    }

    int H  = 2*hp + r2;
    int qo = (r1 << 1) | r0;
    if (r3 == 0) wx_s[slot][H][jq * 4 + qo] = F;   // 32 lanes, 32 chunks
    if (lane == 0) { dn_s[slot][2*hp+0] = d0; dn_s[slot][2*hp+1] = d1; }
    __syncthreads();   // single barrier, after ALL global loads are consumed

    // ---- fused V-projection epilogue: 2 passes (one per slot) ----
    #pragma unroll
    for (int s = 0; s < 2; ++s) {
        int col = tid;                   // 0..255 = h*64 + k
        int h = col >> 6;                // wave-uniform
        float inv = 1.f / dn_s[s][h];
        const float* wvc = Wv + col;     // Wv[j*HK + col], coalesced, L2-hot
        float acc = 0.f;
        #pragma unroll
        for (int j4 = 0; j4 < 16; ++j4) {
            float4 w4 = wx_s[s][h][j4];  // wave-uniform broadcast
            acc = fmaf(w4.x, wvc[(size_t)(j4*4+0) * HK],
                  fmaf(w4.y, wvc[(size_t)(j4*4+1) * HK],
                  fmaf(w4.z, wvc[(size_t)(j4*4+2) * HK],
                  fmaf(w4.w, wvc[(size_t)(j4*4+3) * HK], acc))));
        }
        out[(size_t)(blockIdx.x * 2 + s) * HK + col] = acc * inv;
    }
}

extern "C" void kernel_launch(void* const* d_in, const int* in_sizes, int n_in,
                              void* d_out, int out_size, void* d_ws, size_t ws_size,
                              hipStream_t stream) {
    const float* q_x  = (const float*)d_in[0];   // [16,128,256]
    const float* kv_x = (const float*)d_in[1];   // [16,128,127,64]
    const float* Wq   = (const float*)d_in[2];   // [256,256]
    const float* Wk   = (const float*)d_in[3];   // [64,256]
    const float* Wv   = (const float*)d_in[4];   // [64,256]
    float* out = (float*)d_out;                  // [16,128,256] f32

    float* qk = (float*)d_ws;                    // BT*HK floats = 2 MB

    qk_fused <<<BT / 4, 256, 0, stream>>>(q_x, Wq, Wk, qk);
    attn_fused<<<BT / 2, 256, 0, stream>>>(kv_x, qk, Wv, out);
}